// Round 7
// baseline (412.670 us; speedup 1.0000x reference)
//
#include <hip/hip_runtime.h>
#include <stdint.h>

#define NTHREADS 512
#define BM 64
#define LDSS 520            // LDS row stride in bf16 elems: 1040 B, 16B-aligned, bank offset 4/row
#define DIM 512
#define LDS_BYTES (2 * BM * LDSS * 2)

typedef __attribute__((ext_vector_type(8))) short short8;
typedef __attribute__((ext_vector_type(4))) float floatx4;
typedef __attribute__((ext_vector_type(4))) int intx4;
typedef __attribute__((ext_vector_type(2))) int intx2;

static __device__ __forceinline__ uint32_t f2bf(float f) {
    uint32_t u = __float_as_uint(f);
    return (u + 0x7fffu + ((u >> 16) & 1u)) >> 16;   // RNE fp32->bf16
}

// Repack w_qkv (512x1536 fp32, row-major [k][n]) into bf16 MFMA-B-fragment order.
// Fragment space: nb in [0,96) (16-col blocks in *repacked* col order), kk in [0,16),
// lane in [0,64), e in [0,8).  flat = ((nb*16+kk)*64+lane)*8+e
// repacked col n: chunk0 = Q natural (i*32+d), chunk1 = K natural, chunk2 = V transposed (d*16+j)
__global__ void repack_qkv_k(const float* __restrict__ w, ushort* __restrict__ rp) {
    int f = blockIdx.x * 256 + threadIdx.x;          // [0, 786432)
    int e = f & 7, lane = (f >> 3) & 63, kk = (f >> 9) & 15, nb = f >> 13;
    int n = nb * 16 + (lane & 15);
    int k = kk * 32 + (lane >> 4) * 8 + e;
    int c = n >> 9, cc = n & 511;
    int ocol = (c == 0) ? cc
             : (c == 1) ? (512 + cc)
                        : (1024 + (cc & 15) * 32 + (cc >> 4));
    rp[f] = (ushort)f2bf(w[k * 1536 + ocol]);
}

__global__ void repack_out_k(const float* __restrict__ w, ushort* __restrict__ rp) {
    int f = blockIdx.x * 256 + threadIdx.x;          // [0, 262144)
    int e = f & 7, lane = (f >> 3) & 63, kk = (f >> 9) & 15, nb = f >> 13;
    int n = nb * 16 + (lane & 15);
    int k = kk * 32 + (lane >> 4) * 8 + e;
    rp[f] = (ushort)f2bf(w[k * 512 + n]);
}

__global__ __launch_bounds__(NTHREADS, 2)
void fused_win_attn(const float* __restrict__ x, const ushort* __restrict__ rpq,
                    const ushort* __restrict__ rpo, const float* __restrict__ bo,
                    float* __restrict__ out)
{
    extern __shared__ ushort lds[];
    ushort* Xs = lds;                 // [64][520] bf16: X tile, later reused as attn-out tile
    ushort* CB = lds + BM * LDSS;     // [64][520] bf16: Q / K / V^T chunk (reused 3x)

    const int tid = threadIdx.x;
    const int w   = tid >> 6;         // wave 0..7
    const int l   = tid & 63;
    const int i16 = l & 15;
    const int g   = l >> 4;
    const long rowbase = (long)blockIdx.x * BM;

    // ---- stage X tile: fp32 -> bf16 -> LDS ----
    {
        const float* xs = x + rowbase * DIM;
        #pragma unroll
        for (int it = 0; it < 8; ++it) {
            int e = (it * NTHREADS + tid) * 8;       // elem idx in 64x512 tile
            int r = e >> 9, c = e & 511;
            const float4* p = (const float4*)(xs + e);
            float4 v0 = p[0], v1 = p[1];
            intx4 t;
            t[0] = (int)(f2bf(v0.x) | (f2bf(v0.y) << 16));
            t[1] = (int)(f2bf(v0.z) | (f2bf(v0.w) << 16));
            t[2] = (int)(f2bf(v1.x) | (f2bf(v1.y) << 16));
            t[3] = (int)(f2bf(v1.z) | (f2bf(v1.w) << 16));
            *(intx4*)&Xs[r * LDSS + c] = t;
        }
    }
    __syncthreads();

    // One 64x64 GEMM tile per wave: A from Xs (64 rows), B fragments direct from global
    // (repacked, L2-resident).  K = 512 (16 ksteps of 32).
    auto run_gemm = [&](const ushort* wb, floatx4 (&acc)[4][4]) {
        short8 bcur[4];
        #pragma unroll
        for (int n = 0; n < 4; ++n)
            bcur[n] = *(const short8*)(wb + n * 16 * 512);
        #pragma unroll 4
        for (int kk = 0; kk < 16; ++kk) {
            short8 bnxt[4];
            if (kk < 15) {
                #pragma unroll
                for (int n = 0; n < 4; ++n)
                    bnxt[n] = *(const short8*)(wb + (n * 16 + kk + 1) * 512);
            }
            short8 af[4];
            #pragma unroll
            for (int m = 0; m < 4; ++m)
                af[m] = *(const short8*)&Xs[(m * 16 + i16) * LDSS + kk * 32 + g * 8];
            #pragma unroll
            for (int m = 0; m < 4; ++m) {
                #pragma unroll
                for (int n = 0; n < 4; ++n)
                    acc[m][n] = __builtin_amdgcn_mfma_f32_16x16x32_bf16(
                        af[m], bcur[n], acc[m][n], 0, 0, 0);
            }
            if (kk < 15) {
                #pragma unroll
                for (int n = 0; n < 4; ++n) bcur[n] = bnxt[n];
            }
        }
    };

    auto store_chunk = [&](floatx4 (&acc)[4][4]) {
        #pragma unroll
        for (int m = 0; m < 4; ++m) {
            #pragma unroll
            for (int n = 0; n < 4; ++n) {
                #pragma unroll
                for (int p = 0; p < 4; ++p)
                    CB[(m * 16 + 4 * g + p) * LDSS + w * 64 + n * 16 + i16] =
                        (ushort)f2bf(acc[m][n][p]);
            }
        }
    };

    // ---- chunk 0: Q (natural layout i*32+d) ----
    {
        floatx4 acc[4][4] = {};
        run_gemm(rpq + (size_t)(0 * 32 + w * 4) * 8192 + (size_t)l * 8, acc);
        store_chunk(acc);
    }
    __syncthreads();

    // grab this wave's 8 rows' Q B-fragments into registers (lane: Q[i16, 8g..8g+8))
    short8 qf[8];
    #pragma unroll
    for (int rr = 0; rr < 8; ++rr)
        qf[rr] = *(const short8*)&CB[(w * 8 + rr) * LDSS + i16 * 32 + g * 8];
    __syncthreads();

    // ---- chunk 1: K ----
    {
        floatx4 acc[4][4] = {};
        run_gemm(rpq + (size_t)(1 * 32 + w * 4) * 8192 + (size_t)l * 8, acc);
        store_chunk(acc);
    }
    __syncthreads();

    // ---- dots^T = K·Q^T per row; softmax over j (lane-local 4 regs + shfl 16/32) ----
    uint32_t pk0[8], pk1[8];
    #pragma unroll
    for (int rr = 0; rr < 8; ++rr) {
        short8 kf = *(const short8*)&CB[(w * 8 + rr) * LDSS + i16 * 32 + g * 8];
        floatx4 d = {0.f, 0.f, 0.f, 0.f};
        d = __builtin_amdgcn_mfma_f32_16x16x32_bf16(kf, qf[rr], d, 0, 0, 0);
        const float scale = 0.17677669529663689f;   // 32^-0.5
        float d0 = d[0] * scale, d1 = d[1] * scale, d2 = d[2] * scale, d3 = d[3] * scale;
        float mx = fmaxf(fmaxf(d0, d1), fmaxf(d2, d3));
        mx = fmaxf(mx, __shfl_xor(mx, 16, 64));
        mx = fmaxf(mx, __shfl_xor(mx, 32, 64));
        float e0 = __expf(d0 - mx), e1 = __expf(d1 - mx);
        float e2 = __expf(d2 - mx), e3 = __expf(d3 - mx);
        float s = e0 + e1 + e2 + e3;
        s += __shfl_xor(s, 16, 64);
        s += __shfl_xor(s, 32, 64);
        float inv = 1.0f / s;
        pk0[rr] = f2bf(e0 * inv) | (f2bf(e1 * inv) << 16);   // lane holds P[i16, 4g+p]
        pk1[rr] = f2bf(e2 * inv) | (f2bf(e3 * inv) << 16);
    }
    __syncthreads();

    // ---- chunk 2: V (repacked transposed: CB[r][d*16+j]) ----
    {
        floatx4 acc[4][4] = {};
        run_gemm(rpq + (size_t)(2 * 32 + w * 4) * 8192 + (size_t)l * 8, acc);
        store_chunk(acc);
    }
    __syncthreads();

    // ---- PV: out^T = V^T·P^T per row (K=16 zero-padded to 32); write bf16 to Xs ----
    #pragma unroll
    for (int rr = 0; rr < 8; ++rr) {
        int r = w * 8 + rr;
        // assemble B-frag (P[k=j, n=i]) from the 4 lanes holding column i16's probs
        int srcA = i16 + 32 * (g & 1);
        uint32_t w0 = __shfl(pk0[rr], srcA, 64);
        uint32_t w1 = __shfl(pk1[rr], srcA, 64);
        uint32_t w2 = __shfl(pk0[rr], srcA + 16, 64);
        uint32_t w3 = __shfl(pk1[rr], srcA + 16, 64);
        if (g >= 2) { w0 = 0; w1 = 0; w2 = 0; w3 = 0; }   // j >= 16 pad
        union { uint32_t u[4]; short8 s; } pu;
        pu.u[0] = w0; pu.u[1] = w1; pu.u[2] = w2; pu.u[3] = w3;
        short8 pfrag = pu.s;
        #pragma unroll
        for (int c2 = 0; c2 < 2; ++c2) {                   // d-halves 0..15 / 16..31
            short8 vf = {0, 0, 0, 0, 0, 0, 0, 0};
            if (g < 2)
                vf = *(const short8*)&CB[r * LDSS + (i16 + 16 * c2) * 16 + g * 8];
            floatx4 o = {0.f, 0.f, 0.f, 0.f};
            o = __builtin_amdgcn_mfma_f32_16x16x32_bf16(vf, pfrag, o, 0, 0, 0);
            // lane holds out[i=i16, d=16*c2+4g+p] -> pack 4 bf16, store 8 B
            intx2 t;
            t[0] = (int)(f2bf(o[0]) | (f2bf(o[1]) << 16));
            t[1] = (int)(f2bf(o[2]) | (f2bf(o[3]) << 16));
            *(intx2*)&Xs[r * LDSS + i16 * 32 + 16 * c2 + 4 * g] = t;
        }
    }
    __syncthreads();

    // ---- GEMM2: (attn out in Xs) @ w_out + bias, fp32 store ----
    {
        floatx4 acc[4][4] = {};
        run_gemm(rpo + (size_t)(w * 4) * 8192 + (size_t)l * 8, acc);
        #pragma unroll
        for (int n = 0; n < 4; ++n) {
            float bias = bo[w * 64 + n * 16 + i16];
            #pragma unroll
            for (int m = 0; m < 4; ++m) {
                #pragma unroll
                for (int p = 0; p < 4; ++p)
                    out[(rowbase + m * 16 + 4 * g + p) * DIM + w * 64 + n * 16 + i16] =
                        acc[m][n][p] + bias;
            }
        }
    }
}

extern "C" void kernel_launch(void* const* d_in, const int* in_sizes, int n_in,
                              void* d_out, int out_size, void* d_ws, size_t ws_size,
                              hipStream_t stream) {
    const float* x     = (const float*)d_in[0];
    const float* w_qkv = (const float*)d_in[1];
    const float* w_out = (const float*)d_in[2];
    const float* b_out = (const float*)d_in[3];
    float* outp = (float*)d_out;

    ushort* rpq = (ushort*)d_ws;            // 786432 bf16 = 1.5 MB
    ushort* rpo = rpq + 786432;             // 262144 bf16 = 0.5 MB

    repack_qkv_k<<<3072, 256, 0, stream>>>(w_qkv, rpq);
    repack_out_k<<<1024, 256, 0, stream>>>(w_out, rpo);

    hipFuncSetAttribute((const void*)fused_win_attn,
                        hipFuncAttributeMaxDynamicSharedMemorySize, LDS_BYTES);
    fused_win_attn<<<dim3(65536 / BM), dim3(NTHREADS), LDS_BYTES, stream>>>(
        x, rpq, rpo, b_out, outp);
}